// Round 11
// baseline (218.731 us; speedup 1.0000x reference)
//
#include <hip/hip_runtime.h>

typedef __bf16 bf16;
typedef __bf16 bf16x8 __attribute__((ext_vector_type(8)));
typedef __bf16 bf16x4 __attribute__((ext_vector_type(4)));
typedef float f32x4 __attribute__((ext_vector_type(4)));
typedef unsigned long long u64;

#define MFMA16(a, b, c) __builtin_amdgcn_mfma_f32_16x16x32_bf16(a, b, c, 0, 0, 0)

// Async global->LDS, 16 B/lane; LDS dest = wave-uniform base + lane*16.
__device__ __forceinline__ void gl_lds16(const void* g, void* l) {
  __builtin_amdgcn_global_load_lds(
      (const __attribute__((address_space(1))) unsigned int*)g,
      (__attribute__((address_space(3))) unsigned int*)l, 16, 0, 0);
}

template <int N>
__device__ __forceinline__ void wait_vmcnt() {
  asm volatile("s_waitcnt vmcnt(%0)" ::"n"(N) : "memory");
}

// Compiler-fenced raw barrier (no vmcnt drain, unlike __syncthreads).
__device__ __forceinline__ void bar() {
  asm volatile("" ::: "memory");
  __builtin_amdgcn_s_barrier();
  asm volatile("" ::: "memory");
}

// Hardware exp2: single v_exp_f32 (libm exp2f without -ffast-math lowers to
// a guarded OCML sequence).
__device__ __forceinline__ float hw_exp2(float x) {
#if __has_builtin(__builtin_amdgcn_exp2f)
  return __builtin_amdgcn_exp2f(x);
#else
  float r;
  asm("v_exp_f32 %0, %1" : "=v"(r) : "v"(x));
  return r;
#endif
}

// ---------------------------------------------------------------------------
// Prep (shrunk: x/context downcasts ELIMINATED — QKV stages f32 directly):
//   blocks    0..1023: weight transpose+downcast (Wq,Wkv -> BqkvT; Wp -> WpT)
//   blocks 1024..1279: mask pack -> u64 bit-words
// ---------------------------------------------------------------------------
__global__ __launch_bounds__(256)
void prep_k(const float* __restrict__ Wq, const float* __restrict__ Wkv,
            const float* __restrict__ Wp, const int* __restrict__ mask,
            bf16* __restrict__ BqkvT, bf16* __restrict__ WpT,
            u64* __restrict__ maskbits) {
  const int bx = blockIdx.x;
  const int tid = threadIdx.x;
  if (bx >= 1024) {  // ---- mask pack
    const int idx = (bx - 1024) * 256 + tid;
    const int4* p = (const int4*)(mask + (size_t)idx * 64);
    u64 v = 0;
#pragma unroll
    for (int i = 0; i < 16; ++i) {
      int4 m = p[i];
      v |= (u64)(m.x != 0) << (4 * i);
      v |= (u64)(m.y != 0) << (4 * i + 1);
      v |= (u64)(m.z != 0) << (4 * i + 2);
      v |= (u64)(m.w != 0) << (4 * i + 3);
    }
    maskbits[idx] = v;
    return;
  }
  // ---- weight transpose tile
  const int ct = bx >> 4, rt = bx & 15;
  const float* src;
  bf16* dst;
  int C, c0, drow0;
  if (ct < 16) {
    src = Wq; C = 1024; c0 = ct * 64; dst = BqkvT; drow0 = c0;
  } else if (ct < 48) {
    src = Wkv; C = 2048; c0 = (ct - 16) * 64; dst = BqkvT; drow0 = 1024 + c0;
  } else {
    src = Wp; C = 1024; c0 = (ct - 48) * 64; dst = WpT; drow0 = c0;
  }
  __shared__ bf16 T[64][72];
  const int r0 = rt * 64;
#pragma unroll
  for (int i = 0; i < 2; ++i) {
    int c = i * 256 + tid;
    int row = c >> 3, col = (c & 7) * 8;
    const float* sp = &src[(size_t)(r0 + row) * C + c0 + col];
    f32x4 a0 = *(const f32x4*)sp;
    f32x4 a1 = *(const f32x4*)(sp + 4);
    bf16x8 t;
#pragma unroll
    for (int j = 0; j < 4; ++j) { t[j] = (bf16)a0[j]; t[4 + j] = (bf16)a1[j]; }
    *(bf16x8*)&T[row][col] = t;
  }
  __syncthreads();
#pragma unroll
  for (int i = 0; i < 2; ++i) {
    int c = i * 256 + tid;
    int orow = c >> 3, ocol = (c & 7) * 8;
    bf16x8 v;
#pragma unroll
    for (int j = 0; j < 8; ++j) v[j] = T[ocol + j][orow];
    *(bf16x8*)&dst[(size_t)(drow0 + orow) * 1024 + r0 + ocol] = v;
  }
}

// ---------------------------------------------------------------------------
// QKV GEMM, f32-A-direct: db2 structure (2 LDS buffers, one __syncthreads
// per K-step, next tile's global_load_lds in flight across current MFMAs)
// with A staged as RAW F32 via global_load_lds (bytes are bytes) and
// converted to bf16 at fragment-read time (bit-identical to the old
// downcast-then-load path). Kills the 48 MB x/context downcast round-trip.
//   LDS: Asf 2x16 KB (f32) + Bs 2x8 KB (bf16) = 48 KB -> 3 blocks/CU.
//   A swizzle: rows are 128 B = 8 granules; stage fetches logical granule
//   (lane&7)^(lane>>3) into phys lane&7 -> phys = logical ^ (row&7); read
//   at phys = gl ^ (l15&7). Per quarter-wave (fixed l4, one b128): 8
//   distinct granules x broadcast pairs -> conflict-free.
//   B side identical to the proven kernels. Epilogue scatters Q*SCALE2/K/V^T.
// ---------------------------------------------------------------------------
__global__ __launch_bounds__(256, 3)
void gemm_qkvf(const float* __restrict__ x, const float* __restrict__ ctx,
               const bf16* __restrict__ Bt, const float* __restrict__ bq,
               const float* __restrict__ bkv, bf16* __restrict__ oq,
               bf16* __restrict__ ok, bf16* __restrict__ ovt) {
  __shared__ float Asf[2][128][32];  // 32 KB
  __shared__ bf16 Bs[2][128][32];    // 16 KB
  const int tid = threadIdx.x;
  const int lane = tid & 63;
  const int w = tid >> 6;
  const int wm = (w >> 1) * 64;
  const int wn = (w & 1) * 64;
  const int l15 = lane & 15, l4 = lane >> 4;
  // B staging coords (bf16 rows = 64 B = 4 granules; 4 lanes/row).
  const int lrow = lane >> 2;
  const int lcg = (lane & 3) ^ ((lrow >> 1) & 3);
  const int rdc = (l4 ^ ((l15 >> 1) & 3)) * 8;  // B read col (bf16 elems)
  // A staging coords (f32 rows = 128 B = 8 granules; 8 lanes/row).
  const int arow = lane >> 3;              // row within 8-row issue group
  const int alg = (lane & 7) ^ arow;       // logical granule to fetch
  const int s7 = l15 & 7;                  // read-side row key
  const int m0 = blockIdx.x * 128;  // m fastest -> XCD = m%8
  const int n0 = blockIdx.y * 128;

  const float* Af = (n0 < 1024) ? x : ctx;

  // Bias preload.
  float bc[4];
#pragma unroll
  for (int j = 0; j < 4; ++j) {
    const int col = n0 + wn + j * 16 + l15;
    bc[j] = (col < 1024) ? bq[col] : bkv[col - 1024];
  }

  f32x4 acc[4][4] = {};

#define STAGE(kk, buf)                                                        \
  {                                                                           \
    _Pragma("unroll") for (int it = 0; it < 4; ++it) {                        \
      const int rb = w * 32 + it * 8;                                         \
      gl_lds16(&Af[(size_t)(m0 + rb + arow) * 1024 + (kk) + alg * 4],         \
               &Asf[buf][rb][0]);                                             \
    }                                                                         \
    _Pragma("unroll") for (int it = 0; it < 2; ++it) {                        \
      const int r = w * 32 + it * 16;                                         \
      gl_lds16(&Bt[(size_t)(n0 + r + lrow) * 1024 + (kk) + lcg * 8],          \
               &Bs[buf][r][0]);                                               \
    }                                                                         \
  }

#define COMPUTE(buf)                                                          \
  {                                                                           \
    bf16x8 af[4], bfr[4];                                                     \
    _Pragma("unroll") for (int i = 0; i < 4; ++i) {                           \
      const float* ap = &Asf[buf][wm + i * 16 + l15][0];                      \
      f32x4 a0 = *(const f32x4*)(ap + (((2 * l4) ^ s7) * 4));                 \
      f32x4 a1 = *(const f32x4*)(ap + (((2 * l4 + 1) ^ s7) * 4));             \
      bf16x8 t;                                                               \
      _Pragma("unroll") for (int u = 0; u < 4; ++u) {                         \
        t[u] = (bf16)a0[u];                                                   \
        t[4 + u] = (bf16)a1[u];                                               \
      }                                                                       \
      af[i] = t;                                                              \
    }                                                                         \
    _Pragma("unroll") for (int j = 0; j < 4; ++j) bfr[j] =                    \
        *(const bf16x8*)&Bs[buf][wn + j * 16 + l15][rdc];                     \
    _Pragma("unroll") for (int i = 0; i < 4; ++i)                             \
        _Pragma("unroll") for (int j = 0; j < 4; ++j) acc[i][j] =             \
            MFMA16(af[i], bfr[j], acc[i][j]);                                 \
  }

  STAGE(0, 0);
  for (int k = 0; k < 32; k += 2) {
    __syncthreads();  // tile k staged
    STAGE((k + 1) * 32, 1);  // in flight across COMPUTE(0)
    COMPUTE(0);
    __syncthreads();  // tile k+1 staged
    if (k < 30) STAGE((k + 2) * 32, 0);
    COMPUTE(1);
  }
#undef STAGE
#undef COMPUTE

  const float SCALE2 = 0.18033688011112042f;  // 1/sqrt(64) * log2(e)
#pragma unroll
  for (int j = 0; j < 4; ++j) {
    const int col = n0 + wn + j * 16 + l15;
#pragma unroll
    for (int i = 0; i < 4; ++i) {
#pragma unroll
      for (int r = 0; r < 4; ++r) {
        const int row = m0 + wm + i * 16 + l4 * 4 + r;
        const float v = acc[i][j][r] + bc[j];
        const int b = row >> 10, n = row & 1023;
        if (col < 1024) {
          const int h = col >> 6, d = col & 63;
          oq[(((size_t)(b * 16 + h)) * 1024 + n) * 64 + d] = (bf16)(v * SCALE2);
        } else {
          const int ckv = col - 1024;
          const int s = ckv >> 10, c2 = ckv & 1023;
          const int h = c2 >> 6, d = c2 & 63;
          if (s == 0)
            ok[(((size_t)(b * 16 + h)) * 1024 + n) * 64 + d] = (bf16)v;
          else
            ovt[(((size_t)(b * 16 + h)) * 64 + d) * 1024 + n] = (bf16)v;
        }
      }
    }
  }
}

// ---------------------------------------------------------------------------
// Pipelined GEMM v3 (round-4 proven, OUTPUT projection): 128x64, BK=32,
// 3 LDS buffers, counted vmcnt, raw barriers. 36 KB -> 4 blocks/CU.
// ---------------------------------------------------------------------------
template <int EPI, int BN>
__global__ __launch_bounds__(256, BN == 128 ? 3 : 4)
void gemm_p3(const bf16* __restrict__ A0, const bf16* __restrict__ A1,
             const bf16* __restrict__ Bt, const float* __restrict__ bias0,
             const float* __restrict__ bias1, bf16* __restrict__ oq,
             bf16* __restrict__ ok, bf16* __restrict__ ovt,
             float* __restrict__ outf) {
  constexpr int NJ = BN / 32;      // 16-wide n-frags per wave
  constexpr int S = 2 + BN / 64;   // global_load_lds per thread per stage
  __shared__ bf16 As[3][128][32];
  __shared__ bf16 Bs[3][BN][32];
  const int tid = threadIdx.x;
  const int lane = tid & 63;
  const int w = tid >> 6;
  const int wm = (w >> 1) * 64;
  const int wn = (w & 1) * (BN / 2);
  const int l15 = lane & 15, l4 = lane >> 4;
  const int lrow = lane >> 2;
  const int lcg = (lane & 3) ^ ((lrow >> 1) & 3);
  const int rdc = (l4 ^ ((l15 >> 1) & 3)) * 8;
  const int m0 = blockIdx.x * 128;  // m fastest -> XCD = m%8
  const int n0 = blockIdx.y * BN;

  const bf16* Asrc = (EPI == 1) ? ((n0 < 1024) ? A0 : A1) : A0;

  float bc[NJ];
#pragma unroll
  for (int j = 0; j < NJ; ++j) {
    const int col = n0 + wn + j * 16 + l15;
    if (EPI == 1) bc[j] = (col < 1024) ? bias0[col] : bias1[col - 1024];
    else bc[j] = bias0[col];
  }

  f32x4 acc[4][NJ] = {};

#define STAGE(kk, buf)                                                        \
  {                                                                           \
    _Pragma("unroll") for (int it = 0; it < 2; ++it) {                        \
      const int r = w * 32 + it * 16;                                         \
      gl_lds16(&Asrc[(size_t)(m0 + r + lrow) * 1024 + (kk) + lcg * 8],        \
               &As[buf][r][0]);                                               \
    }                                                                         \
    _Pragma("unroll") for (int it = 0; it < BN / 64; ++it) {                  \
      const int r = w * (BN / 4) + it * 16;                                   \
      gl_lds16(&Bt[(size_t)(n0 + r + lrow) * 1024 + (kk) + lcg * 8],          \
               &Bs[buf][r][0]);                                               \
    }                                                                         \
  }

#define COMPUTE(buf)                                                          \
  {                                                                           \
    bf16x8 af[4], bfr[NJ];                                                    \
    _Pragma("unroll") for (int i = 0; i < 4; ++i) af[i] =                     \
        *(const bf16x8*)&As[buf][wm + i * 16 + l15][rdc];                     \
    _Pragma("unroll") for (int j = 0; j < NJ; ++j) bfr[j] =                   \
        *(const bf16x8*)&Bs[buf][wn + j * 16 + l15][rdc];                     \
    _Pragma("unroll") for (int i = 0; i < 4; ++i)                             \
        _Pragma("unroll") for (int j = 0; j < NJ; ++j) acc[i][j] =            \
            MFMA16(af[i], bfr[j], acc[i][j]);                                 \
  }

  STAGE(0, 0);
  STAGE(32, 1);
#pragma unroll 3
  for (int k = 0; k < 30; ++k) {
    wait_vmcnt<S>();
    bar();
    STAGE((k + 2) * 32, (k + 2) % 3);
    COMPUTE(k % 3);
  }
  wait_vmcnt<S>();
  bar();
  COMPUTE(0);
  wait_vmcnt<0>();
  bar();
  COMPUTE(1);
#undef STAGE
#undef COMPUTE

  const float SCALE2 = 0.18033688011112042f;  // 1/sqrt(64) * log2(e)
#pragma unroll
  for (int j = 0; j < NJ; ++j) {
    const int col = n0 + wn + j * 16 + l15;
#pragma unroll
    for (int i = 0; i < 4; ++i) {
#pragma unroll
      for (int r = 0; r < 4; ++r) {
        const int row = m0 + wm + i * 16 + l4 * 4 + r;
        const float v = acc[i][j][r] + bc[j];
        if (EPI == 0) {
          outf[(size_t)row * 1024 + col] = v;
        } else {
          const int b = row >> 10, n = row & 1023;
          if (col < 1024) {
            const int h = col >> 6, d = col & 63;
            oq[(((size_t)(b * 16 + h)) * 1024 + n) * 64 + d] =
                (bf16)(v * SCALE2);
          } else {
            const int ckv = col - 1024;
            const int s = ckv >> 10, c2 = ckv & 1023;
            const int h = c2 >> 6, d = c2 & 63;
            if (s == 0)
              ok[(((size_t)(b * 16 + h)) * 1024 + n) * 64 + d] = (bf16)v;
            else
              ovt[(((size_t)(b * 16 + h)) * 64 + d) * 1024 + n] = (bf16)v;
          }
        }
      }
    }
  }
}

// ---------------------------------------------------------------------------
// Attention v3.2 (round-10 proven): QBLK=128, grid (64,8), swapped QK^T,
// shared K/V frags, hw_exp2, 32-bit nibble mask, no s-init, XOR-swizzled
// gl_lds staging, dbuf, mask prefetch, 1 syncthreads/mt. LDS 48 KB.
// ---------------------------------------------------------------------------
__global__ __launch_bounds__(256, 2)
void attn_kernel(const bf16* __restrict__ q, const bf16* __restrict__ k,
                 const bf16* __restrict__ vT, const u64* __restrict__ maskbits,
                 bf16* __restrict__ ao) {
  const int bh = blockIdx.x;
  const int ntile = blockIdx.y;  // 0..7
  const int b = bh >> 4, h = bh & 15;
  const int tid = threadIdx.x;
  const int lane = tid & 63;
  const int w = tid >> 6;
  const int l15 = lane & 15, l4 = lane >> 4;

  __shared__ bf16 Ks[2][64][64];
  __shared__ bf16 Vts[2][64][64];
  __shared__ bf16 Pw[4][32][64];

  const size_t base = (size_t)bh * 65536;
  const int nrow0 = ntile * 128 + w * 32;

  bf16x8 qf[2][2];
#pragma unroll
  for (int f = 0; f < 2; ++f)
#pragma unroll
    for (int ks = 0; ks < 2; ++ks)
      qf[f][ks] = *(const bf16x8*)&q[base +
                                     (size_t)(nrow0 + f * 16 + l15) * 64 +
                                     ks * 32 + l4 * 8];

  const u64* mb = maskbits + (size_t)(b * 1024 + nrow0 + l15) * 16;

  const int srow = lane >> 3;
  const int sgl = (lane & 7) ^ srow;
  const bf16* kp = &k[base + (size_t)(w * 16 + srow) * 64 + sgl * 8];
  const bf16* vp = &vT[base + (size_t)(w * 16 + srow) * 1024 + sgl * 8];

  const int rc0 = ((0 + l4) ^ (l15 & 7)) * 8;
  const int rc1 = ((4 + l4) ^ (l15 & 7)) * 8;

  const int sh0 = l4 * 4;        // sub even
  const int sh1 = 16 + l4 * 4;   // sub odd

  f32x4 o[2][4] = {};
  float lsum[2] = {0.0f, 0.0f};

#define STAGEA(mt_, buf_)                                                     \
  {                                                                           \
    _Pragma("unroll") for (int it = 0; it < 2; ++it) {                        \
      gl_lds16(kp + (size_t)((mt_)*64 + it * 8) * 64,                         \
               &Ks[buf_][w * 16 + it * 8][0]);                                \
      gl_lds16(vp + (size_t)(it * 8) * 1024 + (mt_)*64,                       \
               &Vts[buf_][w * 16 + it * 8][0]);                               \
    }                                                                         \
  }

  STAGEA(0, 0);
  u64 wm0 = mb[0];
  u64 wm1 = mb[256];
  for (int mt = 0; mt < 16; ++mt) {
    const int cur = mt & 1;
    __syncthreads();
    if (mt < 15) STAGEA(mt + 1, cur ^ 1);
    u64 nm0 = 0, nm1 = 0;
    if (mt < 15) {
      nm0 = mb[mt + 1];
      nm1 = mb[256 + mt + 1];
    }

    f32x4 s[2][4];
    __builtin_amdgcn_s_setprio(1);
#pragma unroll
    for (int sub = 0; sub < 4; ++sub) {
      bf16x8 kf0 = *(const bf16x8*)&Ks[cur][sub * 16 + l15][rc0];
      bf16x8 kf1 = *(const bf16x8*)&Ks[cur][sub * 16 + l15][rc1];
      s[0][sub] = MFMA16(kf0, qf[0][0], (f32x4)0.0f);
      s[0][sub] = MFMA16(kf1, qf[0][1], s[0][sub]);
      s[1][sub] = MFMA16(kf0, qf[1][0], (f32x4)0.0f);
      s[1][sub] = MFMA16(kf1, qf[1][1], s[1][sub]);
    }
    __builtin_amdgcn_s_setprio(0);

#pragma unroll
    for (int f = 0; f < 2; ++f) {
      const u64 wmt = f ? wm1 : wm0;
      const unsigned mlo = (unsigned)wmt;
      const unsigned mhi = (unsigned)(wmt >> 32);
#pragma unroll
      for (int sub = 0; sub < 4; ++sub) {
        const unsigned word = (sub < 2) ? mlo : mhi;
        const unsigned nib = (word >> ((sub & 1) ? sh1 : sh0)) & 15u;
        float p[4];
#pragma unroll
        for (int r = 0; r < 4; ++r) {
          float e = hw_exp2(s[f][sub][r]);
          p[r] = ((nib >> r) & 1u) ? e : 0.0f;
        }
        lsum[f] += (p[0] + p[1]) + (p[2] + p[3]);
        bf16x4 pv;
#pragma unroll
        for (int r = 0; r < 4; ++r) pv[r] = (bf16)p[r];
        const int gw = sub * 2 + (l4 >> 1);
        char* pd = (char*)&Pw[w][f * 16 + l15][0] +
                   ((gw ^ (l15 & 7)) * 16 + (l4 & 1) * 8);
        *(bf16x4*)pd = pv;
      }
    }

    bf16x8 af[2][2];
#pragma unroll
    for (int f = 0; f < 2; ++f) {
      af[f][0] = *(const bf16x8*)&Pw[w][f * 16 + l15][rc0];
      af[f][1] = *(const bf16x8*)&Pw[w][f * 16 + l15][rc1];
    }
    __builtin_amdgcn_s_setprio(1);
#pragma unroll
    for (int sub = 0; sub < 4; ++sub) {
      bf16x8 vf0 = *(const bf16x8*)&Vts[cur][sub * 16 + l15][rc0];
      bf16x8 vf1 = *(const bf16x8*)&Vts[cur][sub * 16 + l15][rc1];
      o[0][sub] = MFMA16(af[0][0], vf0, o[0][sub]);
      o[0][sub] = MFMA16(af[0][1], vf1, o[0][sub]);
      o[1][sub] = MFMA16(af[1][0], vf0, o[1][sub]);
      o[1][sub] = MFMA16(af[1][1], vf1, o[1][sub]);
    }
    __builtin_amdgcn_s_setprio(0);

    wm0 = nm0;
    wm1 = nm1;
  }
#undef STAGEA

  float inv[2][4];
#pragma unroll
  for (int f = 0; f < 2; ++f) {
    float t = lsum[f];
    t += __shfl_xor(t, 16);
    t += __shfl_xor(t, 32);
#pragma unroll
    for (int r = 0; r < 4; ++r) inv[f][r] = 1.0f / __shfl(t, l4 * 4 + r);
  }

#pragma unroll
  for (int f = 0; f < 2; ++f) {
#pragma unroll
    for (int sub = 0; sub < 4; ++sub) {
#pragma unroll
      for (int r = 0; r < 4; ++r) {
        const int n = nrow0 + f * 16 + l4 * 4 + r;
        const size_t idx =
            ((size_t)(b * 1024 + n)) * 1024 + h * 64 + sub * 16 + l15;
        ao[idx] = (bf16)(o[f][sub][r] * inv[f][r]);
      }
    }
  }
}

// ---------------------------------------------------------------------------
extern "C" void kernel_launch(void* const* d_in, const int* in_sizes, int n_in,
                              void* d_out, int out_size, void* d_ws,
                              size_t ws_size, hipStream_t stream) {
  const float* x = (const float*)d_in[0];        // [4,1024,1024]
  const float* context = (const float*)d_in[1];  // [4,1024,1024]
  const int* mask = (const int*)d_in[2];         // [4,1024,32,32]
  const float* Wq = (const float*)d_in[3];
  const float* bq = (const float*)d_in[4];
  const float* Wkv = (const float*)d_in[5];
  const float* bkv = (const float*)d_in[6];
  const float* Wp = (const float*)d_in[7];
  const float* bp = (const float*)d_in[8];
  float* out = (float*)d_out;                    // [4,1024,1024] f32

  // Workspace (40.5 MB):
  //  @0    (8 MB): aow (attn out -> OP input)
  //  @8    (6 MB): BqkvT
  //  @14   (8 MB): qw   @22 (8 MB): kw   @30 (8 MB): vtw
  //  @38 (0.5 MB): maskbits   @38.5 (2 MB): WpT
  char* ws = (char*)d_ws;
  bf16* aow = (bf16*)(ws);
  bf16* BqkvT = (bf16*)(ws + (8ull << 20));
  bf16* qw = (bf16*)(ws + (14ull << 20));
  bf16* kw = (bf16*)(ws + (22ull << 20));
  bf16* vtw = (bf16*)(ws + (30ull << 20));
  u64* maskbits = (u64*)(ws + (38ull << 20));
  bf16* WpT = (bf16*)(ws + (38ull << 20) + (512ull << 10));

  const dim3 blk(256);

  // Prep: weight transposes + mask pack only (downcasts eliminated).
  prep_k<<<dim3(1280), blk, 0, stream>>>(Wq, Wkv, Wp, mask, BqkvT, WpT,
                                         maskbits);

  // Fused QKV projection: f32-A-direct db2, grid (m=32, n=24), 3 blk/CU.
  gemm_qkvf<<<dim3(32, 24), blk, 0, stream>>>(x, context, BqkvT, bq, bkv,
                                              qw, kw, vtw);

  // Attention v3.2: QBLK=128, grid (bh=64, ntile=8) -> XCD = bh%8.
  attn_kernel<<<dim3(64, 8), blk, 0, stream>>>(qw, kw, vtw, maskbits, aow);

  // Output projection: pipelined v3, grid (m=32, n=16), 4 blk/CU.
  gemm_p3<0, 64><<<dim3(32, 16), blk, 0, stream>>>(aow, nullptr, WpT, bp,
                                                   nullptr, nullptr, nullptr,
                                                   nullptr, out);
}

// Round 13
// 203.890 us; speedup vs baseline: 1.0728x; 1.0728x over previous
//
#include <hip/hip_runtime.h>

typedef __bf16 bf16;
typedef __bf16 bf16x8 __attribute__((ext_vector_type(8)));
typedef __bf16 bf16x4 __attribute__((ext_vector_type(4)));
typedef float f32x4 __attribute__((ext_vector_type(4)));
typedef unsigned long long u64;

#define MFMA16(a, b, c) __builtin_amdgcn_mfma_f32_16x16x32_bf16(a, b, c, 0, 0, 0)

// Async global->LDS, 16 B/lane; LDS dest = wave-uniform base + lane*16.
__device__ __forceinline__ void gl_lds16(const void* g, void* l) {
  __builtin_amdgcn_global_load_lds(
      (const __attribute__((address_space(1))) unsigned int*)g,
      (__attribute__((address_space(3))) unsigned int*)l, 16, 0, 0);
}

template <int N>
__device__ __forceinline__ void wait_vmcnt() {
  asm volatile("s_waitcnt vmcnt(%0)" ::"n"(N) : "memory");
}

// Compiler-fenced raw barrier (no vmcnt drain, unlike __syncthreads).
__device__ __forceinline__ void bar() {
  asm volatile("" ::: "memory");
  __builtin_amdgcn_s_barrier();
  asm volatile("" ::: "memory");
}

// Hardware exp2: single v_exp_f32 (libm exp2f without -ffast-math lowers to
// a guarded OCML sequence).
__device__ __forceinline__ float hw_exp2(float x) {
#if __has_builtin(__builtin_amdgcn_exp2f)
  return __builtin_amdgcn_exp2f(x);
#else
  float r;
  asm("v_exp_f32 %0, %1" : "=v"(r) : "v"(x));
  return r;
#endif
}

// ---------------------------------------------------------------------------
// Fused prep (round-3/10 proven — the downcast passes are REQUIRED: they buy
// the bf16 64B-row LDS geometry whose bank mapping rotates with row parity;
// R11's f32-direct staging proved 128B rows conflict 8-way regardless of
// swizzle, 3.1M conflicts):
//   blocks    0..1023: weight transpose+downcast (Wq,Wkv -> BqkvT; Wp -> WpT)
//   blocks 1024..1279: mask pack -> u64 bit-words
//   blocks 1280..3327: context f32 -> bf16 (cb)
//   blocks 3328..5375: x f32 -> bf16 (xb)
// ---------------------------------------------------------------------------
__global__ __launch_bounds__(256)
void prep_k(const float* __restrict__ Wq, const float* __restrict__ Wkv,
            const float* __restrict__ Wp, const int* __restrict__ mask,
            const float* __restrict__ context, const float* __restrict__ x,
            bf16* __restrict__ BqkvT, bf16* __restrict__ WpT,
            u64* __restrict__ maskbits, bf16* __restrict__ cb,
            bf16* __restrict__ xb) {
  const int bx = blockIdx.x;
  const int tid = threadIdx.x;
  if (bx >= 3328) {  // ---- x downcast
    const size_t i = ((size_t)(bx - 3328) * 256 + tid) * 8;
    f32x4 a0 = *(const f32x4*)(x + i);
    f32x4 a1 = *(const f32x4*)(x + i + 4);
    bf16x8 t;
#pragma unroll
    for (int j = 0; j < 4; ++j) { t[j] = (bf16)a0[j]; t[4 + j] = (bf16)a1[j]; }
    *(bf16x8*)(xb + i) = t;
    return;
  }
  if (bx >= 1280) {  // ---- context downcast
    const size_t i = ((size_t)(bx - 1280) * 256 + tid) * 8;
    f32x4 a0 = *(const f32x4*)(context + i);
    f32x4 a1 = *(const f32x4*)(context + i + 4);
    bf16x8 t;
#pragma unroll
    for (int j = 0; j < 4; ++j) { t[j] = (bf16)a0[j]; t[4 + j] = (bf16)a1[j]; }
    *(bf16x8*)(cb + i) = t;
    return;
  }
  if (bx >= 1024) {  // ---- mask pack
    const int idx = (bx - 1024) * 256 + tid;
    const int4* p = (const int4*)(mask + (size_t)idx * 64);
    u64 v = 0;
#pragma unroll
    for (int i = 0; i < 16; ++i) {
      int4 m = p[i];
      v |= (u64)(m.x != 0) << (4 * i);
      v |= (u64)(m.y != 0) << (4 * i + 1);
      v |= (u64)(m.z != 0) << (4 * i + 2);
      v |= (u64)(m.w != 0) << (4 * i + 3);
    }
    maskbits[idx] = v;
    return;
  }
  // ---- weight transpose tile
  const int ct = bx >> 4, rt = bx & 15;
  const float* src;
  bf16* dst;
  int C, c0, drow0;
  if (ct < 16) {
    src = Wq; C = 1024; c0 = ct * 64; dst = BqkvT; drow0 = c0;
  } else if (ct < 48) {
    src = Wkv; C = 2048; c0 = (ct - 16) * 64; dst = BqkvT; drow0 = 1024 + c0;
  } else {
    src = Wp; C = 1024; c0 = (ct - 48) * 64; dst = WpT; drow0 = c0;
  }
  __shared__ bf16 T[64][72];
  const int r0 = rt * 64;
#pragma unroll
  for (int i = 0; i < 2; ++i) {
    int c = i * 256 + tid;
    int row = c >> 3, col = (c & 7) * 8;
    const float* sp = &src[(size_t)(r0 + row) * C + c0 + col];
    f32x4 a0 = *(const f32x4*)sp;
    f32x4 a1 = *(const f32x4*)(sp + 4);
    bf16x8 t;
#pragma unroll
    for (int j = 0; j < 4; ++j) { t[j] = (bf16)a0[j]; t[4 + j] = (bf16)a1[j]; }
    *(bf16x8*)&T[row][col] = t;
  }
  __syncthreads();
#pragma unroll
  for (int i = 0; i < 2; ++i) {
    int c = i * 256 + tid;
    int orow = c >> 3, ocol = (c & 7) * 8;
    bf16x8 v;
#pragma unroll
    for (int j = 0; j < 8; ++j) v[j] = T[ocol + j][orow];
    *(bf16x8*)&dst[(size_t)(drow0 + orow) * 1024 + r0 + ocol] = v;
  }
}

// ---------------------------------------------------------------------------
// Pipelined GEMM v3 (round-4/10 proven for both QKV and OP): 128xBN, BK=32,
// 3 LDS buffers (tile t -> buf t%3), stages issued 2 tiles ahead, one raw
// barrier per K-step with counted s_waitcnt vmcnt(S) (never 0 in the loop).
// 16B-granule XOR swizzle on global source + ds_read column (0 conflicts).
// LDS: BN=128 -> 48 KB (3 blk/CU); BN=64 -> 36 KB (4 blk/CU).
// ---------------------------------------------------------------------------
template <int EPI, int BN>
__global__ __launch_bounds__(256, BN == 128 ? 3 : 4)
void gemm_p3(const bf16* __restrict__ A0, const bf16* __restrict__ A1,
             const bf16* __restrict__ Bt, const float* __restrict__ bias0,
             const float* __restrict__ bias1, bf16* __restrict__ oq,
             bf16* __restrict__ ok, bf16* __restrict__ ovt,
             float* __restrict__ outf) {
  constexpr int NJ = BN / 32;      // 16-wide n-frags per wave
  constexpr int S = 2 + BN / 64;   // global_load_lds per thread per stage
  __shared__ bf16 As[3][128][32];
  __shared__ bf16 Bs[3][BN][32];
  const int tid = threadIdx.x;
  const int lane = tid & 63;
  const int w = tid >> 6;
  const int wm = (w >> 1) * 64;
  const int wn = (w & 1) * (BN / 2);
  const int l15 = lane & 15, l4 = lane >> 4;
  const int lrow = lane >> 2;
  const int lcg = (lane & 3) ^ ((lrow >> 1) & 3);
  const int rdc = (l4 ^ ((l15 >> 1) & 3)) * 8;
  const int m0 = blockIdx.x * 128;  // m fastest -> XCD = m%8
  const int n0 = blockIdx.y * BN;

  const bf16* Asrc = (EPI == 1) ? ((n0 < 1024) ? A0 : A1) : A0;

  // Preload bias (issued before any staging -> retires before first wait).
  float bc[NJ];
#pragma unroll
  for (int j = 0; j < NJ; ++j) {
    const int col = n0 + wn + j * 16 + l15;
    if (EPI == 1) bc[j] = (col < 1024) ? bias0[col] : bias1[col - 1024];
    else bc[j] = bias0[col];
  }

  f32x4 acc[4][NJ] = {};

#define STAGE(kk, buf)                                                        \
  {                                                                           \
    _Pragma("unroll") for (int it = 0; it < 2; ++it) {                        \
      const int r = w * 32 + it * 16;                                         \
      gl_lds16(&Asrc[(size_t)(m0 + r + lrow) * 1024 + (kk) + lcg * 8],        \
               &As[buf][r][0]);                                               \
    }                                                                         \
    _Pragma("unroll") for (int it = 0; it < BN / 64; ++it) {                  \
      const int r = w * (BN / 4) + it * 16;                                   \
      gl_lds16(&Bt[(size_t)(n0 + r + lrow) * 1024 + (kk) + lcg * 8],          \
               &Bs[buf][r][0]);                                               \
    }                                                                         \
  }

#define COMPUTE(buf)                                                          \
  {                                                                           \
    bf16x8 af[4], bfr[NJ];                                                    \
    _Pragma("unroll") for (int i = 0; i < 4; ++i) af[i] =                     \
        *(const bf16x8*)&As[buf][wm + i * 16 + l15][rdc];                     \
    _Pragma("unroll") for (int j = 0; j < NJ; ++j) bfr[j] =                   \
        *(const bf16x8*)&Bs[buf][wn + j * 16 + l15][rdc];                     \
    _Pragma("unroll") for (int i = 0; i < 4; ++i)                             \
        _Pragma("unroll") for (int j = 0; j < NJ; ++j) acc[i][j] =            \
            MFMA16(af[i], bfr[j], acc[i][j]);                                 \
  }

  // Prologue: tiles 0 and 1 in flight (2S outstanding).
  STAGE(0, 0);
  STAGE(32, 1);
#pragma unroll 3
  for (int k = 0; k < 30; ++k) {
    wait_vmcnt<S>();  // tile k landed; tile k+1 stays in flight
    bar();
    STAGE((k + 2) * 32, (k + 2) % 3);  // buf free: tile k-1 fully read
    COMPUTE(k % 3);
  }
  wait_vmcnt<S>();
  bar();
  COMPUTE(0);
  wait_vmcnt<0>();
  bar();
  COMPUTE(1);
#undef STAGE
#undef COMPUTE

  const float SCALE2 = 0.18033688011112042f;  // 1/sqrt(64) * log2(e)
#pragma unroll
  for (int j = 0; j < NJ; ++j) {
    const int col = n0 + wn + j * 16 + l15;
#pragma unroll
    for (int i = 0; i < 4; ++i) {
#pragma unroll
      for (int r = 0; r < 4; ++r) {
        const int row = m0 + wm + i * 16 + l4 * 4 + r;
        const float v = acc[i][j][r] + bc[j];
        if (EPI == 0) {
          outf[(size_t)row * 1024 + col] = v;
        } else {
          const int b = row >> 10, n = row & 1023;
          if (col < 1024) {
            const int h = col >> 6, d = col & 63;
            oq[(((size_t)(b * 16 + h)) * 1024 + n) * 64 + d] =
                (bf16)(v * SCALE2);
          } else {
            const int ckv = col - 1024;
            const int s = ckv >> 10, c2 = ckv & 1023;
            const int h = c2 >> 6, d = c2 & 63;
            if (s == 0)
              ok[(((size_t)(b * 16 + h)) * 1024 + n) * 64 + d] = (bf16)v;
            else
              ovt[(((size_t)(b * 16 + h)) * 64 + d) * 1024 + n] = (bf16)v;
          }
        }
      }
    }
  }
}

// ---------------------------------------------------------------------------
// Attention v4: QBLK=64 (16 q-rows/wave) + the full round-10 VALU diet.
// Rationale: v3.2 (QBLK=128) is VALU-bound at only 2 blocks/CU (2 waves/SIMD,
// VALUBusy ~50% = half the issue slots idle on dependency chains). Total
// softmax VALU work is fixed per q-row, so the lever is waves/SIMD:
// LDS = Ks 16K + Vts 16K + Pw 8K = 40 KB -> exactly 4 blocks/CU, grid
// (64,16) = 1024 blocks = 4/CU = 4 waves/SIMD. Staging doubles but K/V are
// L2-resident (HBM was 6%) and staging was never the bound.
// Diet kept: hw_exp2, 32-bit nibble mask, zero-C s-init, mask prefetch,
// swapped QK^T, XOR-swizzled gl_lds staging, dbuf, 1 syncthreads/mt.
// ---------------------------------------------------------------------------
__global__ __launch_bounds__(256, 4)
void attn_kernel(const bf16* __restrict__ q, const bf16* __restrict__ k,
                 const bf16* __restrict__ vT, const u64* __restrict__ maskbits,
                 bf16* __restrict__ ao) {
  const int bh = blockIdx.x;
  const int ntile = blockIdx.y;  // 0..15
  const int b = bh >> 4, h = bh & 15;
  const int tid = threadIdx.x;
  const int lane = tid & 63;
  const int w = tid >> 6;
  const int l15 = lane & 15, l4 = lane >> 4;

  __shared__ bf16 Ks[2][64][64];
  __shared__ bf16 Vts[2][64][64];
  __shared__ bf16 Pw[4][16][64];

  const size_t base = (size_t)bh * 65536;
  const int nrow0 = ntile * 64 + w * 16;

  // Q B-fragments (q-row = nrow0 + l15). Pre-scaled by SCALE2 in QKV.
  bf16x8 qf[2];
#pragma unroll
  for (int ks = 0; ks < 2; ++ks)
    qf[ks] = *(const bf16x8*)&q[base + (size_t)(nrow0 + l15) * 64 + ks * 32 +
                                l4 * 8];

  // Per-lane mask row (q-row = l15); one u64 per mt, prefetched 1 ahead.
  const u64* mb = maskbits + (size_t)(b * 1024 + nrow0 + l15) * 16;

  // K/V staging: lane -> row (i>>3), phys granule i&7; source fetches
  // logical granule (i&7)^(row&7) so phys = logical ^ (row&7).
  const int srow = lane >> 3;
  const int sgl = (lane & 7) ^ srow;
  const bf16* kp = &k[base + (size_t)(w * 16 + srow) * 64 + sgl * 8];
  const bf16* vp = &vT[base + (size_t)(w * 16 + srow) * 1024 + sgl * 8];

  // Fragment read columns: logical granule ks*4+l4 -> phys ^= (l15&7).
  const int rc0 = ((0 + l4) ^ (l15 & 7)) * 8;
  const int rc1 = ((4 + l4) ^ (l15 & 7)) * 8;

  // Nibble shift amounts for the 32-bit mask words.
  const int sh0 = l4 * 4;        // sub even
  const int sh1 = 16 + l4 * 4;   // sub odd

  f32x4 o[4] = {};
  float lsum = 0.0f;

#define STAGEA(mt_, buf_)                                                     \
  {                                                                           \
    _Pragma("unroll") for (int it = 0; it < 2; ++it) {                        \
      gl_lds16(kp + (size_t)((mt_)*64 + it * 8) * 64,                         \
               &Ks[buf_][w * 16 + it * 8][0]);                                \
      gl_lds16(vp + (size_t)(it * 8) * 1024 + (mt_)*64,                       \
               &Vts[buf_][w * 16 + it * 8][0]);                               \
    }                                                                         \
  }

  STAGEA(0, 0);
  u64 wm0 = mb[0];
  for (int mt = 0; mt < 16; ++mt) {
    const int cur = mt & 1;
    __syncthreads();  // drains staging for tile mt (and mask prefetch)
    if (mt < 15) STAGEA(mt + 1, cur ^ 1);  // in flight across compute
    u64 nm0 = 0;
    if (mt < 15) nm0 = mb[mt + 1];

    // S^T: lane holds q = l15, k = sub*16 + l4*4 + r. Zero-C first MFMA.
    f32x4 s[4];
    __builtin_amdgcn_s_setprio(1);
#pragma unroll
    for (int sub = 0; sub < 4; ++sub) {
      bf16x8 kf0 = *(const bf16x8*)&Ks[cur][sub * 16 + l15][rc0];
      bf16x8 kf1 = *(const bf16x8*)&Ks[cur][sub * 16 + l15][rc1];
      s[sub] = MFMA16(kf0, qf[0], (f32x4)0.0f);
      s[sub] = MFMA16(kf1, qf[1], s[sub]);
    }
    __builtin_amdgcn_s_setprio(0);

    // Softmax + P pack: one ds_write_b64 per sub. 32-bit nibble mask.
    const unsigned mlo = (unsigned)wm0;
    const unsigned mhi = (unsigned)(wm0 >> 32);
#pragma unroll
    for (int sub = 0; sub < 4; ++sub) {
      const unsigned word = (sub < 2) ? mlo : mhi;
      const unsigned nib = (word >> ((sub & 1) ? sh1 : sh0)) & 15u;
      float p[4];
#pragma unroll
      for (int r = 0; r < 4; ++r) {
        float e = hw_exp2(s[sub][r]);
        p[r] = ((nib >> r) & 1u) ? e : 0.0f;
      }
      lsum += (p[0] + p[1]) + (p[2] + p[3]);
      bf16x4 pv;
#pragma unroll
      for (int r = 0; r < 4; ++r) pv[r] = (bf16)p[r];
      const int gw = sub * 2 + (l4 >> 1);
      char* pd = (char*)&Pw[w][l15][0] + ((gw ^ (l15 & 7)) * 16 + (l4 & 1) * 8);
      *(bf16x4*)pd = pv;
    }

    // PV: A = P (row=q=l15), B = V (n=d=l15).
    bf16x8 af0 = *(const bf16x8*)&Pw[w][l15][rc0];
    bf16x8 af1 = *(const bf16x8*)&Pw[w][l15][rc1];
    __builtin_amdgcn_s_setprio(1);
#pragma unroll
    for (int sub = 0; sub < 4; ++sub) {
      bf16x8 vf0 = *(const bf16x8*)&Vts[cur][sub * 16 + l15][rc0];
      bf16x8 vf1 = *(const bf16x8*)&Vts[cur][sub * 16 + l15][rc1];
      o[sub] = MFMA16(af0, vf0, o[sub]);
      o[sub] = MFMA16(af1, vf1, o[sub]);
    }
    __builtin_amdgcn_s_setprio(0);

    wm0 = nm0;
  }
#undef STAGEA

  // lsum at lane q=l15: reduce over l4 groups, redistribute to output
  // layout (q = l4*4 + r).
  float t = lsum;
  t += __shfl_xor(t, 16);
  t += __shfl_xor(t, 32);
  float inv[4];
#pragma unroll
  for (int r = 0; r < 4; ++r) inv[r] = 1.0f / __shfl(t, l4 * 4 + r);

#pragma unroll
  for (int sub = 0; sub < 4; ++sub) {
#pragma unroll
    for (int r = 0; r < 4; ++r) {
      const int n = nrow0 + l4 * 4 + r;
      const size_t idx =
          ((size_t)(b * 1024 + n)) * 1024 + h * 64 + sub * 16 + l15;
      ao[idx] = (bf16)(o[sub][r] * inv[r]);
    }
  }
}

// ---------------------------------------------------------------------------
extern "C" void kernel_launch(void* const* d_in, const int* in_sizes, int n_in,
                              void* d_out, int out_size, void* d_ws,
                              size_t ws_size, hipStream_t stream) {
  const float* x = (const float*)d_in[0];        // [4,1024,1024]
  const float* context = (const float*)d_in[1];  // [4,1024,1024]
  const int* mask = (const int*)d_in[2];         // [4,1024,32,32]
  const float* Wq = (const float*)d_in[3];
  const float* bq = (const float*)d_in[4];
  const float* Wkv = (const float*)d_in[5];
  const float* bkv = (const float*)d_in[6];
  const float* Wp = (const float*)d_in[7];
  const float* bp = (const float*)d_in[8];
  float* out = (float*)d_out;                    // [4,1024,1024] f32

  // Workspace (48.5 MB):
  //  @0    (8 MB): cb (prep->QKV), dead after QKV -> aow reuses it
  //  @8    (8 MB): xb (prep->QKV), dead after QKV
  //  @16   (6 MB): BqkvT (prep->QKV)
  //  @22   (8 MB): qw   @30 (8 MB): kw   @38 (8 MB): vtw
  //  @46 (0.5 MB): maskbits   @46.5 (2 MB): WpT
  char* ws = (char*)d_ws;
  bf16* cb = (bf16*)(ws);
  bf16* aow = (bf16*)(ws);
  bf16* xb = (bf16*)(ws + (8ull << 20));
  bf16* BqkvT = (bf16*)(ws + (16ull << 20));
  bf16* qw = (bf16*)(ws + (22ull << 20));
  bf16* kw = (bf16*)(ws + (30ull << 20));
  bf16* vtw = (bf16*)(ws + (38ull << 20));
  u64* maskbits = (u64*)(ws + (46ull << 20));
  bf16* WpT = (bf16*)(ws + (46ull << 20) + (512ull << 10));

  const dim3 blk(256);

  // Prep: weight transposes + mask pack + context/x downcast, one launch.
  prep_k<<<dim3(5376), blk, 0, stream>>>(Wq, Wkv, Wp, mask, context, x, BqkvT,
                                         WpT, maskbits, cb, xb);

  // Fused QKV projection: pipelined v3, grid (m=32, n=24), 3 blk/CU.
  gemm_p3<1, 128><<<dim3(32, 24), blk, 0, stream>>>(xb, cb, BqkvT, bq, bkv,
                                                    qw, kw, vtw, nullptr);

  // Attention v4: QBLK=64, grid (bh=64, ntile=16) -> XCD = bh%8, 4 blk/CU.
  attn_kernel<<<dim3(64, 16), blk, 0, stream>>>(qw, kw, vtw, maskbits, aow);

  // Output projection: pipelined v3, grid (m=32, n=16), 4 blk/CU.
  gemm_p3<0, 64><<<dim3(32, 16), blk, 0, stream>>>(aow, nullptr, WpT, bp,
                                                   nullptr, nullptr, nullptr,
                                                   nullptr, out);
}